// Round 1
// baseline (457.889 us; speedup 1.0000x reference)
//
#include <hip/hip_runtime.h>
#include <hip/hip_bf16.h>

typedef unsigned short u16;
typedef __attribute__((ext_vector_type(8))) short bf16x8;
typedef __attribute__((ext_vector_type(4))) float f32x4;

#define T_STEPS 64
#define BN_TOT  8192
#define BM      32
#define HPAD    136   // 128 + 8 pad bf16 elems -> 272B rows, 16B aligned

// workspace byte offsets
#define OFF_WHH0  0u
#define OFF_WIH0  131072u
#define OFF_W1    163840u
#define OFF_B0    425984u
#define OFF_B1    428032u
#define OFF_WEFF  430080u
#define OFF_BEFF  432128u
#define OFF_XB    432192u

#define LDS_BYTES (131072 + 2*BM*HPAD*2)   // 148480

__device__ __forceinline__ u16 f2bu(float f) {
  unsigned u = __float_as_uint(f);
  unsigned r = (u + 0x7FFFu + ((u >> 16) & 1u)) >> 16;
  return (u16)r;
}
__device__ __forceinline__ float bu2f(u16 u) {
  return __uint_as_float(((unsigned)u) << 16);
}
__device__ __forceinline__ float fsig(float x) {
  return 1.0f / (1.0f + __expf(-x));
}
__device__ __forceinline__ float ftanhf(float x) {
  float e = __expf(2.0f * x);
  return 1.0f - 2.0f / (e + 1.0f);   // NaN-free saturation at +-1
}
__device__ __forceinline__ f32x4 mfma16(bf16x8 a, bf16x8 b, f32x4 c) {
  return __builtin_amdgcn_mfma_f32_16x16x32_bf16(a, b, c, 0, 0, 0);
}

union U16x8 { u16 u[8]; uint4 q; };

// ---------------- prep: weights -> fragment-ordered bf16, collapsed head ----
__global__ void lstm_prep_w(const float* Wih0, const float* Whh0,
                            const float* bih0, const float* bhh0,
                            const float* Wih1, const float* Whh1,
                            const float* bih1, const float* bhh1,
                            const float* muW1, const float* mub1,
                            const float* muW2, const float* mub2,
                            const float* sgW1, const float* sgb1,
                            const float* sgW2, const float* sgb2,
                            unsigned char* ws)
{
  int id = blockIdx.x * 256 + threadIdx.x;
  u16* whh0_f = (u16*)(ws + OFF_WHH0);
  u16* wih0_f = (u16*)(ws + OFF_WIH0);
  u16* w1_f   = (u16*)(ws + OFF_W1);
  float* b0   = (float*)(ws + OFF_B0);
  float* b1   = (float*)(ws + OFF_B1);
  float* weff = (float*)(ws + OFF_WEFF);
  float* beff = (float*)(ws + OFF_BEFF);

  if (id < 8192) {                       // Whh0 frags: [w][g][kf][lane][8]
    int fid = id >> 6, lane = id & 63;
    int w = fid >> 4, g = (fid >> 2) & 3, kf = fid & 3;
    int r = g*128 + w*16 + (lane & 15);
    int k = kf*32 + (lane >> 4)*8;
    const float* src = Whh0 + r*128 + k;
    U16x8 t;
    #pragma unroll
    for (int i = 0; i < 8; ++i) t.u[i] = f2bu(src[i]);
    ((uint4*)whh0_f)[id] = t.q;
  } else if (id < 10240) {               // Wih0 frags (K=8 in 32, zero-padded)
    int c = id - 8192; int fid = c >> 6, lane = c & 63;
    int w = fid >> 2, g = fid & 3;
    U16x8 t;
    #pragma unroll
    for (int i = 0; i < 8; ++i) t.u[i] = 0;
    if (lane < 16) {
      int r = g*128 + w*16 + lane;
      #pragma unroll
      for (int i = 0; i < 8; ++i) t.u[i] = f2bu(Wih0[r*8 + i]);
    }
    ((uint4*)wih0_f)[c] = t.q;
  } else if (id < 26624) {               // W1 = [Wih1 ; Whh1] frags, K=256
    int c = id - 10240; int fid = c >> 6, lane = c & 63;
    int w = fid >> 5, g = (fid >> 3) & 3, kf = fid & 7;
    int r = g*128 + w*16 + (lane & 15);
    int k = kf*32 + (lane >> 4)*8;
    const float* src = (k < 128) ? (Wih1 + r*128 + k) : (Whh1 + r*128 + (k-128));
    U16x8 t;
    #pragma unroll
    for (int i = 0; i < 8; ++i) t.u[i] = f2bu(src[i]);
    ((uint4*)w1_f)[c] = t.q;
  } else if (id < 27136) {               // b0 arranged
    int i = id - 26624; int w = i >> 6, g = (i >> 4) & 3, cc = i & 15;
    int r = g*128 + w*16 + cc;
    b0[i] = bih0[r] + bhh0[r];
  } else if (id < 27648) {               // b1 arranged
    int i = id - 27136; int w = i >> 6, g = (i >> 4) & 3, cc = i & 15;
    int r = g*128 + w*16 + cc;
    b1[i] = bih1[r] + bhh1[r];
  } else if (id < 28160) {               // collapsed head W: [4][128]
    int i = id - 27648; int o = i >> 7, k = i & 127;
    const float* W1p = (o < 2) ? muW1 : sgW1;
    const float* W2p = (o < 2) ? muW2 : sgW2;
    int oo = o & 1;
    float s = 0.f;
    for (int m = 0; m < 64; ++m) s += W2p[oo*64 + m] * W1p[m*128 + k];
    weff[i] = s;
  } else if (id < 28164) {               // collapsed head bias [4]
    int o = id - 28160; int oo = o & 1;
    const float* W2p = (o < 2) ? muW2 : sgW2;
    const float* b1p = (o < 2) ? mub1 : sgb1;
    const float* b2p = (o < 2) ? mub2 : sgb2;
    float s = b2p[oo];
    for (int m = 0; m < 64; ++m) s += W2p[oo*64 + m] * b1p[m];
    beff[o] = s;
  }
}

// ---------------- prep: in_tensor [B,T,N,D] fp32 -> xb [T, BN, 8] bf16 ------
__global__ void lstm_prep_x(const float* in, unsigned char* ws)
{
  int id = blockIdx.x * 256 + threadIdx.x;     // < 524288
  if (id >= T_STEPS * BN_TOT) return;
  int t = id >> 13, s = id & 8191, b = s >> 9, n = s & 511;
  const float* src = in + (((b*64) + t)*512 + n)*8;
  U16x8 v;
  #pragma unroll
  for (int i = 0; i < 8; ++i) v.u[i] = f2bu(src[i]);
  *(uint4*)(ws + OFF_XB + (size_t)id * 16) = v.q;
}

// ---------------- main: fused 2-layer LSTM + head, persistent over T --------
__global__ __launch_bounds__(512) void lstm_fused(const unsigned char* ws, float* out)
{
  extern __shared__ unsigned char lds[];
  u16* whh0_lds = (u16*)lds;                       // 128KB frag-ordered
  u16* h_a = (u16*)(lds + 131072);                 // [BM][HPAD] bf16
  u16* h_b = h_a + BM * HPAD;                      // [BM][HPAD] bf16

  const u16* whh0_f = (const u16*)(ws + OFF_WHH0);
  const u16* wih0_f = (const u16*)(ws + OFF_WIH0);
  const u16* w1_f   = (const u16*)(ws + OFF_W1);
  const float* b0a  = (const float*)(ws + OFF_B0);
  const float* b1a  = (const float*)(ws + OFF_B1);
  const float* weff = (const float*)(ws + OFF_WEFF);
  const float* beff = (const float*)(ws + OFF_BEFF);
  const u16* xb     = (const u16*)(ws + OFF_XB);

  const int tid = threadIdx.x;
  const int w = tid >> 6, l = tid & 63;
  const int lrow = l & 15, lk = l >> 4;
  const int s0 = blockIdx.x * BM;

  // stage Whh0 frags into LDS (straight 16B copies, layout identical)
  for (int i = tid; i < 8192; i += 512)
    ((uint4*)whh0_lds)[i] = ((const uint4*)whh0_f)[i];
  // zero h_a / h_b (contiguous)
  for (int i = tid; i < 2*BM*HPAD; i += 512) h_a[i] = 0;

  // persistent register weights: layer-1 (K=256) + Wih0 pad-frags + biases
  bf16x8 w1r[4][8];
  #pragma unroll
  for (int g = 0; g < 4; ++g)
    #pragma unroll
    for (int kf = 0; kf < 8; ++kf)
      w1r[g][kf] = *(const bf16x8*)(w1_f + ((((w*4+g)*8)+kf)*64 + l)*8);
  bf16x8 wih0r[4];
  #pragma unroll
  for (int g = 0; g < 4; ++g)
    wih0r[g] = *(const bf16x8*)(wih0_f + ((w*4+g)*64 + l)*8);
  float b0v[4], b1v[4];
  #pragma unroll
  for (int g = 0; g < 4; ++g) {
    b0v[g] = b0a[w*64 + g*16 + lrow];
    b1v[g] = b1a[w*64 + g*16 + lrow];
  }
  float c_a[2][4] = {{0,0,0,0},{0,0,0,0}};
  float c_b[2][4] = {{0,0,0,0},{0,0,0,0}};

  __syncthreads();

  #pragma unroll 1
  for (int t = 0; t < T_STEPS; ++t) {
    // ---- layer 0: gates = b0 + x@Wih0^T + h_a@Whh0^T -----------------------
    bf16x8 xf0 = {0,0,0,0,0,0,0,0}, xf1 = {0,0,0,0,0,0,0,0};
    if (lk == 0) {
      xf0 = *(const bf16x8*)(xb + (size_t)(t*8192 + s0 + lrow)*8);
      xf1 = *(const bf16x8*)(xb + (size_t)(t*8192 + s0 + 16 + lrow)*8);
    }
    f32x4 acc[2][4];
    #pragma unroll
    for (int g = 0; g < 4; ++g) {
      acc[0][g] = (f32x4){b0v[g], b0v[g], b0v[g], b0v[g]};
      acc[1][g] = (f32x4){b0v[g], b0v[g], b0v[g], b0v[g]};
    }
    #pragma unroll
    for (int g = 0; g < 4; ++g) {
      acc[0][g] = mfma16(xf0, wih0r[g], acc[0][g]);
      acc[1][g] = mfma16(xf1, wih0r[g], acc[1][g]);
    }
    #pragma unroll
    for (int kf = 0; kf < 4; ++kf) {
      bf16x8 a0 = *(const bf16x8*)(h_a + lrow*HPAD      + kf*32 + lk*8);
      bf16x8 a1 = *(const bf16x8*)(h_a + (16+lrow)*HPAD + kf*32 + lk*8);
      #pragma unroll
      for (int g = 0; g < 4; ++g) {
        bf16x8 bfr = *(const bf16x8*)(whh0_lds + ((w*16 + g*4 + kf)*64 + l)*8);
        acc[0][g] = mfma16(a0, bfr, acc[0][g]);
        acc[1][g] = mfma16(a1, bfr, acc[1][g]);
      }
    }
    __syncthreads();                       // all h_a reads done
    #pragma unroll
    for (int mf = 0; mf < 2; ++mf)
      #pragma unroll
      for (int q = 0; q < 4; ++q) {
        float gi = fsig(acc[mf][0][q]);
        float gf = fsig(acc[mf][1][q]);
        float gg = ftanhf(acc[mf][2][q]);
        float go = fsig(acc[mf][3][q]);
        float c  = gf * c_a[mf][q] + gi * gg;
        c_a[mf][q] = c;
        float h  = go * ftanhf(c);
        h_a[(mf*16 + lk*4 + q)*HPAD + w*16 + lrow] = f2bu(h);
      }
    __syncthreads();                       // new h_a visible

    // ---- layer 1: gates = b1 + h_a@Wih1^T + h_b@Whh1^T (K=256 in regs) ----
    #pragma unroll
    for (int g = 0; g < 4; ++g) {
      acc[0][g] = (f32x4){b1v[g], b1v[g], b1v[g], b1v[g]};
      acc[1][g] = (f32x4){b1v[g], b1v[g], b1v[g], b1v[g]};
    }
    #pragma unroll
    for (int kf = 0; kf < 8; ++kf) {
      const u16* hs = (kf < 4) ? h_a : h_b;
      int ko = (kf & 3)*32 + lk*8;
      bf16x8 a0 = *(const bf16x8*)(hs + lrow*HPAD      + ko);
      bf16x8 a1 = *(const bf16x8*)(hs + (16+lrow)*HPAD + ko);
      #pragma unroll
      for (int g = 0; g < 4; ++g) {
        acc[0][g] = mfma16(a0, w1r[g][kf], acc[0][g]);
        acc[1][g] = mfma16(a1, w1r[g][kf], acc[1][g]);
      }
    }
    __syncthreads();                       // all h_b reads done
    #pragma unroll
    for (int mf = 0; mf < 2; ++mf)
      #pragma unroll
      for (int q = 0; q < 4; ++q) {
        float gi = fsig(acc[mf][0][q]);
        float gf = fsig(acc[mf][1][q]);
        float gg = ftanhf(acc[mf][2][q]);
        float go = fsig(acc[mf][3][q]);
        float c  = gf * c_b[mf][q] + gi * gg;
        c_b[mf][q] = c;
        float h  = go * ftanhf(c);
        h_b[(mf*16 + lk*4 + q)*HPAD + w*16 + lrow] = f2bu(h);
      }
    __syncthreads();                       // new h_b visible
  }

  // ---- head: out = sigmoid(h_b_final @ Weff^T + beff), sigma *= 0.5 --------
  if (tid < BM*4) {
    int m = tid >> 2, o = tid & 3;
    const float* wr = weff + o*128;
    float d = beff[o];
    #pragma unroll 4
    for (int kk = 0; kk < 16; ++kk) {
      bf16x8 hv = *(const bf16x8*)(h_b + m*HPAD + kk*8);
      #pragma unroll
      for (int j = 0; j < 8; ++j) d += bu2f((u16)hv[j]) * wr[kk*8 + j];
    }
    float v = fsig(d);
    if (o >= 2) v *= 0.5f;
    int s = s0 + m;
    out[(o >= 2 ? 16384 : 0) + s*2 + (o & 1)] = v;
  }
}

extern "C" void kernel_launch(void* const* d_in, const int* in_sizes, int n_in,
                              void* d_out, int out_size, void* d_ws, size_t ws_size,
                              hipStream_t stream) {
  (void)in_sizes; (void)n_in; (void)out_size; (void)ws_size;
  const float* in_tensor = (const float*)d_in[0];
  const float* Wih0 = (const float*)d_in[1];
  const float* Whh0 = (const float*)d_in[2];
  const float* bih0 = (const float*)d_in[3];
  const float* bhh0 = (const float*)d_in[4];
  const float* Wih1 = (const float*)d_in[5];
  const float* Whh1 = (const float*)d_in[6];
  const float* bih1 = (const float*)d_in[7];
  const float* bhh1 = (const float*)d_in[8];
  const float* muW1 = (const float*)d_in[9];
  const float* mub1 = (const float*)d_in[10];
  const float* muW2 = (const float*)d_in[11];
  const float* mub2 = (const float*)d_in[12];
  const float* sgW1 = (const float*)d_in[13];
  const float* sgb1 = (const float*)d_in[14];
  const float* sgW2 = (const float*)d_in[15];
  const float* sgb2 = (const float*)d_in[16];
  unsigned char* ws = (unsigned char*)d_ws;
  float* out = (float*)d_out;

  lstm_prep_w<<<dim3(111), dim3(256), 0, stream>>>(
      Wih0, Whh0, bih0, bhh0, Wih1, Whh1, bih1, bhh1,
      muW1, mub1, muW2, mub2, sgW1, sgb1, sgW2, sgb2, ws);
  lstm_prep_x<<<dim3(2048), dim3(256), 0, stream>>>(in_tensor, ws);

  (void)hipFuncSetAttribute((const void*)lstm_fused,
                            hipFuncAttributeMaxDynamicSharedMemorySize, LDS_BYTES);
  lstm_fused<<<dim3(256), dim3(512), LDS_BYTES, stream>>>(ws, out);
}

// Round 2
// 279.971 us; speedup vs baseline: 1.6355x; 1.6355x over previous
//
#include <hip/hip_runtime.h>
#include <hip/hip_bf16.h>

typedef unsigned short u16;
typedef __attribute__((ext_vector_type(8))) short bf16x8;
typedef __attribute__((ext_vector_type(4))) float f32x4;

#define T_STEPS 64
#define BN_TOT  8192
#define BM      32
#define HPAD    136   // 128 + 8 pad bf16 elems -> 272B rows, 16B aligned

// workspace byte offsets
#define OFF_WHH0  0u
#define OFF_WIH0  131072u
#define OFF_W1    163840u
#define OFF_B0    425984u
#define OFF_B1    428032u
#define OFF_WEFF  430080u
#define OFF_BEFF  432128u
#define OFF_XB    432192u

#define HBUF      (BM*HPAD)                     // u16 elems per h buffer
#define LDS_BYTES (131072 + 3*HBUF*2)           // 157184

__device__ __forceinline__ u16 f2bu(float f) {
  unsigned u = __float_as_uint(f);
  unsigned r = (u + 0x7FFFu + ((u >> 16) & 1u)) >> 16;
  return (u16)r;
}
__device__ __forceinline__ float bu2f(u16 u) {
  return __uint_as_float(((unsigned)u) << 16);
}
// fast sigmoid/tanh: v_exp_f32 (2^x) + v_rcp_f32, saturate correctly at +-inf
__device__ __forceinline__ float fsig(float x) {
  return __builtin_amdgcn_rcpf(1.0f + __builtin_amdgcn_exp2f(-1.44269504f * x));
}
__device__ __forceinline__ float ftanh(float x) {
  return 1.0f - 2.0f * __builtin_amdgcn_rcpf(__builtin_amdgcn_exp2f(2.88539008f * x) + 1.0f);
}
__device__ __forceinline__ unsigned cvt_pk_bf16(float lo, float hi) {
  unsigned r;
  asm("v_cvt_pk_bf16_f32 %0, %1, %2" : "=v"(r) : "v"(lo), "v"(hi));
  return r;   // r[15:0]=bf16(lo), r[31:16]=bf16(hi)
}
__device__ __forceinline__ f32x4 mfma16(bf16x8 a, bf16x8 b, f32x4 c) {
  return __builtin_amdgcn_mfma_f32_16x16x32_bf16(a, b, c, 0, 0, 0);
}

union U16x8 { u16 u[8]; uint4 q; };

// ---------------- prep: weights -> fragment-ordered bf16, collapsed head ----
__global__ void lstm_prep_w(const float* Wih0, const float* Whh0,
                            const float* bih0, const float* bhh0,
                            const float* Wih1, const float* Whh1,
                            const float* bih1, const float* bhh1,
                            const float* muW1, const float* mub1,
                            const float* muW2, const float* mub2,
                            const float* sgW1, const float* sgb1,
                            const float* sgW2, const float* sgb2,
                            unsigned char* ws)
{
  int id = blockIdx.x * 256 + threadIdx.x;
  u16* whh0_f = (u16*)(ws + OFF_WHH0);
  u16* wih0_f = (u16*)(ws + OFF_WIH0);
  u16* w1_f   = (u16*)(ws + OFF_W1);
  float* b0   = (float*)(ws + OFF_B0);
  float* b1   = (float*)(ws + OFF_B1);
  float* weff = (float*)(ws + OFF_WEFF);
  float* beff = (float*)(ws + OFF_BEFF);

  if (id < 8192) {                       // Whh0 frags: [w][g][kf][lane][8]
    int fid = id >> 6, lane = id & 63;
    int w = fid >> 4, g = (fid >> 2) & 3, kf = fid & 3;
    int r = g*128 + w*16 + (lane & 15);
    int k = kf*32 + (lane >> 4)*8;
    const float* src = Whh0 + r*128 + k;
    U16x8 t;
    #pragma unroll
    for (int i = 0; i < 8; ++i) t.u[i] = f2bu(src[i]);
    ((uint4*)whh0_f)[id] = t.q;
  } else if (id < 10240) {               // Wih0 frags (K=8 in 32, zero-padded)
    int c = id - 8192; int fid = c >> 6, lane = c & 63;
    int w = fid >> 2, g = fid & 3;
    U16x8 t;
    #pragma unroll
    for (int i = 0; i < 8; ++i) t.u[i] = 0;
    if (lane < 16) {
      int r = g*128 + w*16 + lane;
      #pragma unroll
      for (int i = 0; i < 8; ++i) t.u[i] = f2bu(Wih0[r*8 + i]);
    }
    ((uint4*)wih0_f)[c] = t.q;
  } else if (id < 26624) {               // W1 = [Wih1 ; Whh1] frags, K=256
    int c = id - 10240; int fid = c >> 6, lane = c & 63;
    int w = fid >> 5, g = (fid >> 3) & 3, kf = fid & 7;
    int r = g*128 + w*16 + (lane & 15);
    int k = kf*32 + (lane >> 4)*8;
    const float* src = (k < 128) ? (Wih1 + r*128 + k) : (Whh1 + r*128 + (k-128));
    U16x8 t;
    #pragma unroll
    for (int i = 0; i < 8; ++i) t.u[i] = f2bu(src[i]);
    ((uint4*)w1_f)[c] = t.q;
  } else if (id < 27136) {               // b0 arranged
    int i = id - 26624; int w = i >> 6, g = (i >> 4) & 3, cc = i & 15;
    int r = g*128 + w*16 + cc;
    b0[i] = bih0[r] + bhh0[r];
  } else if (id < 27648) {               // b1 arranged
    int i = id - 27136; int w = i >> 6, g = (i >> 4) & 3, cc = i & 15;
    int r = g*128 + w*16 + cc;
    b1[i] = bih1[r] + bhh1[r];
  } else if (id < 28160) {               // collapsed head W: [4][128]
    int i = id - 27648; int o = i >> 7, k = i & 127;
    const float* W1p = (o < 2) ? muW1 : sgW1;
    const float* W2p = (o < 2) ? muW2 : sgW2;
    int oo = o & 1;
    float s = 0.f;
    for (int m = 0; m < 64; ++m) s += W2p[oo*64 + m] * W1p[m*128 + k];
    weff[i] = s;
  } else if (id < 28164) {               // collapsed head bias [4]
    int o = id - 28160; int oo = o & 1;
    const float* W2p = (o < 2) ? muW2 : sgW2;
    const float* b1p = (o < 2) ? mub1 : sgb1;
    const float* b2p = (o < 2) ? mub2 : sgb2;
    float s = b2p[oo];
    for (int m = 0; m < 64; ++m) s += W2p[oo*64 + m] * b1p[m];
    beff[o] = s;
  }
}

// ---------------- prep: in_tensor [B,T,N,D] fp32 -> xb [T, BN, 8] bf16 ------
__global__ void lstm_prep_x(const float* in, unsigned char* ws)
{
  int id = blockIdx.x * 256 + threadIdx.x;     // < 524288
  if (id >= T_STEPS * BN_TOT) return;
  int t = id >> 13, s = id & 8191, b = s >> 9, n = s & 511;
  const float* src = in + (((b*64) + t)*512 + n)*8;
  U16x8 v;
  #pragma unroll
  for (int i = 0; i < 8; ++i) v.u[i] = f2bu(src[i]);
  *(uint4*)(ws + OFF_XB + (size_t)id * 16) = v.q;
}

// ---------------- main: fused 2-layer LSTM + head, persistent over T --------
// __launch_bounds__(512, 2): 2 waves/SIMD -> 256 unified VGPR+AGPR budget,
// so the 160-reg weight set stays resident (round-1 capped at 128 and
// rematerialized global loads every step -> 6.9 GB FETCH_SIZE).
__global__ __launch_bounds__(512, 2) void lstm_fused(const unsigned char* ws, float* out)
{
  extern __shared__ unsigned char lds[];
  u16* whh0_lds = (u16*)lds;                       // 128KB frag-ordered
  u16* h_a  = (u16*)(lds + 131072);                // [BM][HPAD] bf16
  u16* h_b0 = h_a + HBUF;
  u16* h_b1 = h_b0 + HBUF;

  const u16* whh0_f = (const u16*)(ws + OFF_WHH0);
  const u16* wih0_f = (const u16*)(ws + OFF_WIH0);
  const u16* w1_f   = (const u16*)(ws + OFF_W1);
  const float* b0a  = (const float*)(ws + OFF_B0);
  const float* b1a  = (const float*)(ws + OFF_B1);
  const float* weff = (const float*)(ws + OFF_WEFF);
  const float* beff = (const float*)(ws + OFF_BEFF);
  const u16* xb     = (const u16*)(ws + OFF_XB);

  const int tid = threadIdx.x;
  const int w = tid >> 6, l = tid & 63;
  const int lrow = l & 15, lk = l >> 4;
  const int s0 = blockIdx.x * BM;

  // stage Whh0 frags into LDS (straight 16B copies, layout identical)
  for (int i = tid; i < 8192; i += 512)
    ((uint4*)whh0_lds)[i] = ((const uint4*)whh0_f)[i];
  // zero all three h buffers (contiguous)
  for (int i = tid; i < 3*HBUF; i += 512) h_a[i] = 0;

  // persistent register weights: layer-1 (K=256) + Wih0 pad-frags + biases
  bf16x8 w1r[4][8];
  #pragma unroll
  for (int g = 0; g < 4; ++g)
    #pragma unroll
    for (int kf = 0; kf < 8; ++kf)
      w1r[g][kf] = *(const bf16x8*)(w1_f + ((((w*4+g)*8)+kf)*64 + l)*8);
  bf16x8 wih0r[4];
  #pragma unroll
  for (int g = 0; g < 4; ++g)
    wih0r[g] = *(const bf16x8*)(wih0_f + ((w*4+g)*64 + l)*8);
  float b0v[4], b1v[4];
  #pragma unroll
  for (int g = 0; g < 4; ++g) {
    b0v[g] = b0a[w*64 + g*16 + lrow];
    b1v[g] = b1a[w*64 + g*16 + lrow];
  }
  float c_a[2][4] = {{0,0,0,0},{0,0,0,0}};
  float c_b[2][4] = {{0,0,0,0},{0,0,0,0}};

  u16* hb_r = h_b0;   // read buffer for layer-1 h_prev (zero at t=0)
  u16* hb_w = h_b1;   // write buffer for layer-1 h_new

  const int wcol = w*16 + lrow;          // column this thread writes
  __syncthreads();

  #pragma unroll 1
  for (int t = 0; t < T_STEPS; ++t) {
    // ---- layer 0: gates = b0 + x@Wih0^T + h_a@Whh0^T -----------------------
    bf16x8 xf0 = {0,0,0,0,0,0,0,0}, xf1 = {0,0,0,0,0,0,0,0};
    if (lk == 0) {
      xf0 = *(const bf16x8*)(xb + (size_t)(t*8192 + s0 + lrow)*8);
      xf1 = *(const bf16x8*)(xb + (size_t)(t*8192 + s0 + 16 + lrow)*8);
    }
    f32x4 acc[2][4];
    #pragma unroll
    for (int g = 0; g < 4; ++g) {
      acc[0][g] = (f32x4){b0v[g], b0v[g], b0v[g], b0v[g]};
      acc[1][g] = (f32x4){b0v[g], b0v[g], b0v[g], b0v[g]};
    }
    #pragma unroll
    for (int g = 0; g < 4; ++g) {
      acc[0][g] = mfma16(xf0, wih0r[g], acc[0][g]);
      acc[1][g] = mfma16(xf1, wih0r[g], acc[1][g]);
    }
    #pragma unroll
    for (int kf = 0; kf < 4; ++kf) {
      bf16x8 a0 = *(const bf16x8*)(h_a + lrow*HPAD      + kf*32 + lk*8);
      bf16x8 a1 = *(const bf16x8*)(h_a + (16+lrow)*HPAD + kf*32 + lk*8);
      #pragma unroll
      for (int g = 0; g < 4; ++g) {
        bf16x8 bfr = *(const bf16x8*)(whh0_lds + ((w*16 + g*4 + kf)*64 + l)*8);
        acc[0][g] = mfma16(a0, bfr, acc[0][g]);
        acc[1][g] = mfma16(a1, bfr, acc[1][g]);
      }
    }
    __syncthreads();                       // (1) WAR: h_a reads done
    #pragma unroll
    for (int mf = 0; mf < 2; ++mf) {
      float hq[4];
      #pragma unroll
      for (int q = 0; q < 4; ++q) {
        float gi = fsig(acc[mf][0][q]);
        float gf = fsig(acc[mf][1][q]);
        float gg = ftanh(acc[mf][2][q]);
        float go = fsig(acc[mf][3][q]);
        float c  = gf * c_a[mf][q] + gi * gg;
        c_a[mf][q] = c;
        hq[q] = go * ftanh(c);
      }
      unsigned p01 = cvt_pk_bf16(hq[0], hq[1]);
      unsigned p23 = cvt_pk_bf16(hq[2], hq[3]);
      int rb = (mf*16 + lk*4)*HPAD + wcol;
      h_a[rb]        = (u16)p01;
      h_a[rb+HPAD]   = (u16)(p01 >> 16);
      h_a[rb+2*HPAD] = (u16)p23;
      h_a[rb+3*HPAD] = (u16)(p23 >> 16);
    }
    __syncthreads();                       // (2) RAW: new h_a visible

    // ---- layer 1: gates = b1 + h_a@Wih1^T + hb_r@Whh1^T (K=256 in regs) ----
    #pragma unroll
    for (int g = 0; g < 4; ++g) {
      acc[0][g] = (f32x4){b1v[g], b1v[g], b1v[g], b1v[g]};
      acc[1][g] = (f32x4){b1v[g], b1v[g], b1v[g], b1v[g]};
    }
    #pragma unroll
    for (int kf = 0; kf < 8; ++kf) {
      const u16* hs = (kf < 4) ? h_a : hb_r;
      int ko = (kf & 3)*32 + lk*8;
      bf16x8 a0 = *(const bf16x8*)(hs + lrow*HPAD      + ko);
      bf16x8 a1 = *(const bf16x8*)(hs + (16+lrow)*HPAD + ko);
      #pragma unroll
      for (int g = 0; g < 4; ++g) {
        acc[0][g] = mfma16(a0, w1r[g][kf], acc[0][g]);
        acc[1][g] = mfma16(a1, w1r[g][kf], acc[1][g]);
      }
    }
    // no WAR barrier needed: writes go to hb_w (ping-pong buffer)
    #pragma unroll
    for (int mf = 0; mf < 2; ++mf) {
      float hq[4];
      #pragma unroll
      for (int q = 0; q < 4; ++q) {
        float gi = fsig(acc[mf][0][q]);
        float gf = fsig(acc[mf][1][q]);
        float gg = ftanh(acc[mf][2][q]);
        float go = fsig(acc[mf][3][q]);
        float c  = gf * c_b[mf][q] + gi * gg;
        c_b[mf][q] = c;
        hq[q] = go * ftanh(c);
      }
      unsigned p01 = cvt_pk_bf16(hq[0], hq[1]);
      unsigned p23 = cvt_pk_bf16(hq[2], hq[3]);
      int rb = (mf*16 + lk*4)*HPAD + wcol;
      hb_w[rb]        = (u16)p01;
      hb_w[rb+HPAD]   = (u16)(p01 >> 16);
      hb_w[rb+2*HPAD] = (u16)p23;
      hb_w[rb+3*HPAD] = (u16)(p23 >> 16);
    }
    __syncthreads();                       // (3) RAW: new h_b visible
    u16* tmp = hb_r; hb_r = hb_w; hb_w = tmp;
  }

  // ---- head: out = sigmoid(h_final @ Weff^T + beff), sigma *= 0.5 ----------
  if (tid < BM*4) {
    int m = tid >> 2, o = tid & 3;
    const float* wr = weff + o*128;
    float d = beff[o];
    #pragma unroll 4
    for (int kk = 0; kk < 16; ++kk) {
      bf16x8 hv = *(const bf16x8*)(hb_r + m*HPAD + kk*8);
      #pragma unroll
      for (int j = 0; j < 8; ++j) d += bu2f((u16)hv[j]) * wr[kk*8 + j];
    }
    float v = fsig(d);
    if (o >= 2) v *= 0.5f;
    int s = s0 + m;
    out[(o >= 2 ? 16384 : 0) + s*2 + (o & 1)] = v;
  }
}

extern "C" void kernel_launch(void* const* d_in, const int* in_sizes, int n_in,
                              void* d_out, int out_size, void* d_ws, size_t ws_size,
                              hipStream_t stream) {
  (void)in_sizes; (void)n_in; (void)out_size; (void)ws_size;
  const float* in_tensor = (const float*)d_in[0];
  const float* Wih0 = (const float*)d_in[1];
  const float* Whh0 = (const float*)d_in[2];
  const float* bih0 = (const float*)d_in[3];
  const float* bhh0 = (const float*)d_in[4];
  const float* Wih1 = (const float*)d_in[5];
  const float* Whh1 = (const float*)d_in[6];
  const float* bih1 = (const float*)d_in[7];
  const float* bhh1 = (const float*)d_in[8];
  const float* muW1 = (const float*)d_in[9];
  const float* mub1 = (const float*)d_in[10];
  const float* muW2 = (const float*)d_in[11];
  const float* mub2 = (const float*)d_in[12];
  const float* sgW1 = (const float*)d_in[13];
  const float* sgb1 = (const float*)d_in[14];
  const float* sgW2 = (const float*)d_in[15];
  const float* sgb2 = (const float*)d_in[16];
  unsigned char* ws = (unsigned char*)d_ws;
  float* out = (float*)d_out;

  lstm_prep_w<<<dim3(111), dim3(256), 0, stream>>>(
      Wih0, Whh0, bih0, bhh0, Wih1, Whh1, bih1, bhh1,
      muW1, mub1, muW2, mub2, sgW1, sgb1, sgW2, sgb2, ws);
  lstm_prep_x<<<dim3(2048), dim3(256), 0, stream>>>(in_tensor, ws);

  (void)hipFuncSetAttribute((const void*)lstm_fused,
                            hipFuncAttributeMaxDynamicSharedMemorySize, LDS_BYTES);
  lstm_fused<<<dim3(256), dim3(512), LDS_BYTES, stream>>>(ws, out);
}